// Round 11
// baseline (118.157 us; speedup 1.0000x reference)
//
#include <hip/hip_runtime.h>
#include <cstdint>
#include <cstddef>

// out[64,197,768] = concat(cls, patchify(images[64,3,224,224]) @ W^T + b)
// v5 = v4 (two-kernel + XCD-bijective swizzle) + 2-phase double-buffered gload_lds
//      pipeline in gemm (T3-minimum): stage tile kt+1 BEFORE computing tile kt, one
//      vmcnt-drain barrier per kt. Staging latency hides under the MFMA phase.
// (Fifth resubmission — rounds 6-10 never ran: GPUAcquisitionTimeout.)
#define MTOT 12544   // 64*196 GEMM rows
#define KTOT 768
#define NTOT 768

typedef float  f32x4  __attribute__((ext_vector_type(4)));
typedef __bf16 bf16x8 __attribute__((ext_vector_type(8)));

// ---------------- Prep: coalesced fp32->bf16 convert (images, W) + cls rows ----------------
#define IMG_ELEMS (64*3*224*224)       // 9,633,792
#define W_ELEMS   (768*768)            // 589,824
#define A_BLOCKS  (IMG_ELEMS/8/256)    // 4704
#define W_BLOCKS  (W_ELEMS/8/256)      // 288
#define CLS_BLOCKS 48                  // 64*768 floats / 4 / 256

__global__ __launch_bounds__(256) void prep_kernel(
    const float* __restrict__ images, const float* __restrict__ Wm,
    const float* __restrict__ cls, float* __restrict__ out,
    __bf16* __restrict__ imgb, __bf16* __restrict__ Wb) {
  const int bid = blockIdx.x, tid = threadIdx.x;
  if (bid < A_BLOCKS) {
    const size_t q = (size_t)bid * 256 + tid;
    const float4 v0 = *(const float4*)(images + q * 8);
    const float4 v1 = *(const float4*)(images + q * 8 + 4);
    bf16x8 o;
    o[0]=(__bf16)v0.x; o[1]=(__bf16)v0.y; o[2]=(__bf16)v0.z; o[3]=(__bf16)v0.w;
    o[4]=(__bf16)v1.x; o[5]=(__bf16)v1.y; o[6]=(__bf16)v1.z; o[7]=(__bf16)v1.w;
    *(bf16x8*)(imgb + q * 8) = o;
  } else if (bid < A_BLOCKS + W_BLOCKS) {
    const size_t q = (size_t)(bid - A_BLOCKS) * 256 + tid;
    const float4 v0 = *(const float4*)(Wm + q * 8);
    const float4 v1 = *(const float4*)(Wm + q * 8 + 4);
    bf16x8 o;
    o[0]=(__bf16)v0.x; o[1]=(__bf16)v0.y; o[2]=(__bf16)v0.z; o[3]=(__bf16)v0.w;
    o[4]=(__bf16)v1.x; o[5]=(__bf16)v1.y; o[6]=(__bf16)v1.z; o[7]=(__bf16)v1.w;
    *(bf16x8*)(Wb + q * 8) = o;
  } else {
    const int t  = (bid - A_BLOCKS - W_BLOCKS) * 256 + tid;
    const int bb = t / 192;             // 192 float4 per row
    const int r  = t - bb * 192;
    *(float4*)(out + (size_t)bb * 197 * 768 + r * 4) = *(const float4*)(cls + r * 4);
  }
}

// ---------------- GEMM: fused patchify-gather + MFMA, 2-phase dbuf ----------------
// BM=64, BN=128, BK=64 -> grid 196*6 = 1176 blocks. LDS 48 KB -> 3 blocks/CU.
#define BM 64
#define BN 128
#define BK 64
#define NBLK_N 6    // 768/128
#define NWG   1176  // (MTOT/BM)*NBLK_N = 8 * 147 exactly
#define WG_PER_XCD 147

__device__ __forceinline__ void gload_lds16(const void* g, void* l) {
  __builtin_amdgcn_global_load_lds((__attribute__((address_space(1))) void*)(g),
                                   (__attribute__((address_space(3))) void*)(l),
                                   16, 0, 0);
}

__global__ __launch_bounds__(256) void gemm_kernel(
    const __bf16* __restrict__ imgb, const __bf16* __restrict__ Wb,
    const float* __restrict__ bias, float* __restrict__ out) {
  __shared__ __bf16 As[2 * 64 * 32 * 2];   // 16 KB: [buf][kstep][row 0..63][k 0..31]
  __shared__ __bf16 Bs[2 * 128 * 32 * 2];  // 32 KB

  const int tid  = threadIdx.x;
  // XCD-bijective swizzle (1176 = 8*147): each XCD owns a contiguous logical range.
  const int bx   = blockIdx.x;
  const int wgid = (bx & 7) * WG_PER_XCD + (bx >> 3);
  // nblk-inner: 6 consecutive wgid (same XCD) share one A-tile; W (2.36 MB) L2-resident.
  const int mblk = wgid / NBLK_N;
  const int nblk = wgid - mblk * NBLK_N;
  const int m0 = mblk * BM;
  const int n0 = nblk * BN;
  const int wave = tid >> 6, lane = tid & 63;
  const int wm = (wave & 1) * 32;   // wave sub-tile 32(M) x 64(N)
  const int wn = (wave >> 1) * 64;
  const int lrow = lane & 15, lq = lane >> 4;

  f32x4 acc[2][4] = {};

  // A staging: 512 16B chunks; chunk c = wave*128 + s*64 + lane
  //   kstep=c>>8, row=(c&255)>>2, jc=c&3 -> k_in_tile = kstep*32+jc*8
  const __bf16* pA[2];
#pragma unroll
  for (int s = 0; s < 2; ++s) {
    const int c = wave * 128 + s * 64 + lane;
    const int kstep = c >> 8, rem = c & 255;
    const int row = rem >> 2, jc = rem & 3;
    const int m = m0 + row;
    const int bb = m / 196, p = m - bb * 196;
    const int pi = p / 14, pj = p - pi * 14;
    const int ph_off = kstep * 2 + (jc >> 1);
    const int pw_off = (jc & 1) * 8;
    const size_t e = ((size_t)(bb * 3 * 224 + pi * 16 + ph_off)) * 224 + pj * 16 + pw_off;
    pA[s] = imgb + e;
  }
  // B staging: 1024 chunks; c = wave*256 + s*64 + lane
  const __bf16* pB[4];
#pragma unroll
  for (int s = 0; s < 4; ++s) {
    const int c = wave * 256 + s * 64 + lane;
    const int kstep = c >> 9, rem = c & 511;
    const int h = rem >> 2, jc = rem & 3;
    pB[s] = Wb + (size_t)(n0 + h) * 768 + kstep * 32 + jc * 8;
  }
  // LDS dests, both buffers
  __bf16* lA[2][2];   // [buf][s]
  __bf16* lB[2][4];
#pragma unroll
  for (int s = 0; s < 2; ++s) {
    const int off = (wave * 128 + s * 64) * 8;
    lA[0][s] = As + off; lA[1][s] = As + 4096 + off;
  }
#pragma unroll
  for (int s = 0; s < 4; ++s) {
    const int off = (wave * 256 + s * 64) * 8;
    lB[0][s] = Bs + off; lB[1][s] = Bs + 8192 + off;
  }

  auto compute = [&](int cur) {
    const __bf16* Ab = As + cur * 4096;
    const __bf16* Bb = Bs + cur * 8192;
#pragma unroll
    for (int ks = 0; ks < 2; ++ks) {
      bf16x8 af[2], bf[4];
#pragma unroll
      for (int i = 0; i < 2; ++i)
        af[i] = *(const bf16x8*)&Ab[ks * 2048 + (wm + i * 16 + lrow) * 32 + lq * 8];
#pragma unroll
      for (int j = 0; j < 4; ++j)
        bf[j] = *(const bf16x8*)&Bb[ks * 4096 + (wn + j * 16 + lrow) * 32 + lq * 8];
#pragma unroll
      for (int i = 0; i < 2; ++i)
#pragma unroll
        for (int j = 0; j < 4; ++j)
          acc[i][j] = __builtin_amdgcn_mfma_f32_16x16x32_bf16(af[i], bf[j], acc[i][j], 0, 0, 0);
    }
  };

  // ---- prologue: stage tile 0 -> buf 0, advance to tile 1
#pragma unroll
  for (int s = 0; s < 2; ++s) gload_lds16(pA[s], lA[0][s]);
#pragma unroll
  for (int s = 0; s < 4; ++s) gload_lds16(pB[s], lB[0][s]);
  pA[0] += 896; pA[1] += 896;
  pB[0] += BK; pB[1] += BK; pB[2] += BK; pB[3] += BK;
  __syncthreads();   // drain vmcnt -> tile 0 complete

  // ---- 2-phase main loop: stage tile kt+1 (other buf), compute tile kt, barrier
  for (int kt = 0; kt < KTOT / BK - 1; ++kt) {   // kt = 0..10
    const int cur = kt & 1, nxt = cur ^ 1;
#pragma unroll
    for (int s = 0; s < 2; ++s) gload_lds16(pA[s], lA[nxt][s]);
#pragma unroll
    for (int s = 0; s < 4; ++s) gload_lds16(pB[s], lB[nxt][s]);
    // advance to tile kt+2 (channel-cross when (kt+1)&3 == 3)
    const int dA = (((kt + 1) & 3) == 3) ? 47488 : 896;
    pA[0] += dA; pA[1] += dA;
    pB[0] += BK; pB[1] += BK; pB[2] += BK; pB[3] += BK;

    compute(cur);
    __syncthreads();   // all waves done reading buf[cur]; tile kt+1 loads drained
  }
  compute(1);          // kt = 11 lives in buf 1; no stage, no barrier needed

  // Epilogue: C/D layout col=lane&15, row=(lane>>4)*4+r (round-0-verified convention)
#pragma unroll
  for (int j = 0; j < 4; ++j) {
    const int h  = n0 + wn + j * 16 + lrow;
    const float bv = bias[h];
#pragma unroll
    for (int i = 0; i < 2; ++i) {
      const int mb = m0 + wm + i * 16 + lq * 4;
#pragma unroll
      for (int r = 0; r < 4; ++r) {
        const int m  = mb + r;
        const int bb = m / 196, p = m - bb * 196;
        out[(size_t)(bb * 197 + 1 + p) * 768 + h] = acc[i][j][r] + bv;
      }
    }
  }
}

extern "C" void kernel_launch(void* const* d_in, const int* in_sizes, int n_in,
                              void* d_out, int out_size, void* d_ws, size_t ws_size,
                              hipStream_t stream) {
  const float* images = (const float*)d_in[0];  // [64,3,224,224]
  const float* Wm     = (const float*)d_in[1];  // [768,768]
  const float* b      = (const float*)d_in[2];  // [768]
  const float* cls    = (const float*)d_in[3];  // [1,768]
  float* out = (float*)d_out;                   // [64,197,768]

  __bf16* imgb = (__bf16*)d_ws;                   // 19.27 MB
  __bf16* Wb   = imgb + (size_t)IMG_ELEMS;        // 1.18 MB
  (void)in_sizes; (void)n_in; (void)out_size; (void)ws_size;

  prep_kernel<<<A_BLOCKS + W_BLOCKS + CLS_BLOCKS, 256, 0, stream>>>(
      images, Wm, cls, out, imgb, Wb);
  gemm_kernel<<<NWG, 256, 0, stream>>>(imgb, Wb, b, out);
}

// Round 12
// 117.401 us; speedup vs baseline: 1.0064x; 1.0064x over previous
//
#include <hip/hip_runtime.h>
#include <cstdint>
#include <cstddef>

// out[64,197,768] = concat(cls, patchify(images[64,3,224,224]) @ W^T + b)
// v6 = v4 + 2-phase pipeline at CONSTANT LDS (24 KB): BK 64->32, both tiles double-
//      buffered (A 2x4KB, B 2x8KB). v5's regression (118.2 vs v4 112.3) attributed to
//      its 48KB LDS cutting residency 6->3 blocks/CU (m114: TLP was doing the hiding).
//      v6 issues tile t+1's global_load_lds BEFORE computing tile t; one barrier/tile;
//      compile-time buffer selection (unroll-by-2, no runtime-indexed arrays).
#define MTOT 12544   // 64*196 GEMM rows
#define KTOT 768
#define NTOT 768

typedef float  f32x4  __attribute__((ext_vector_type(4)));
typedef __bf16 bf16x8 __attribute__((ext_vector_type(8)));

// ---------------- Prep: coalesced fp32->bf16 convert (images, W) + cls rows ----------------
#define IMG_ELEMS (64*3*224*224)       // 9,633,792
#define W_ELEMS   (768*768)            // 589,824
#define A_BLOCKS  (IMG_ELEMS/8/256)    // 4704
#define W_BLOCKS  (W_ELEMS/8/256)      // 288
#define CLS_BLOCKS 48                  // 64*768 floats / 4 / 256

__global__ __launch_bounds__(256) void prep_kernel(
    const float* __restrict__ images, const float* __restrict__ Wm,
    const float* __restrict__ cls, float* __restrict__ out,
    __bf16* __restrict__ imgb, __bf16* __restrict__ Wb) {
  const int bid = blockIdx.x, tid = threadIdx.x;
  if (bid < A_BLOCKS) {
    const size_t q = (size_t)bid * 256 + tid;
    const float4 v0 = *(const float4*)(images + q * 8);
    const float4 v1 = *(const float4*)(images + q * 8 + 4);
    bf16x8 o;
    o[0]=(__bf16)v0.x; o[1]=(__bf16)v0.y; o[2]=(__bf16)v0.z; o[3]=(__bf16)v0.w;
    o[4]=(__bf16)v1.x; o[5]=(__bf16)v1.y; o[6]=(__bf16)v1.z; o[7]=(__bf16)v1.w;
    *(bf16x8*)(imgb + q * 8) = o;
  } else if (bid < A_BLOCKS + W_BLOCKS) {
    const size_t q = (size_t)(bid - A_BLOCKS) * 256 + tid;
    const float4 v0 = *(const float4*)(Wm + q * 8);
    const float4 v1 = *(const float4*)(Wm + q * 8 + 4);
    bf16x8 o;
    o[0]=(__bf16)v0.x; o[1]=(__bf16)v0.y; o[2]=(__bf16)v0.z; o[3]=(__bf16)v0.w;
    o[4]=(__bf16)v1.x; o[5]=(__bf16)v1.y; o[6]=(__bf16)v1.z; o[7]=(__bf16)v1.w;
    *(bf16x8*)(Wb + q * 8) = o;
  } else {
    const int t  = (bid - A_BLOCKS - W_BLOCKS) * 256 + tid;
    const int bb = t / 192;             // 192 float4 per row
    const int r  = t - bb * 192;
    *(float4*)(out + (size_t)bb * 197 * 768 + r * 4) = *(const float4*)(cls + r * 4);
  }
}

// ---------------- GEMM: patchify-gather + MFMA, 2-phase dbuf @ BK=32, 24 KB ----------------
#define BM 64
#define BN 128
#define BK 32
#define NKT 24      // 768/32
#define NBLK_N 6    // 768/128
#define NWG   1176  // (MTOT/BM)*NBLK_N = 8 * 147 exactly
#define WG_PER_XCD 147

__device__ __forceinline__ void gload_lds16(const void* g, void* l) {
  __builtin_amdgcn_global_load_lds((__attribute__((address_space(1))) void*)(g),
                                   (__attribute__((address_space(3))) void*)(l),
                                   16, 0, 0);
}

__global__ __launch_bounds__(256) void gemm_kernel(
    const __bf16* __restrict__ imgb, const __bf16* __restrict__ Wb,
    const float* __restrict__ bias, float* __restrict__ out) {
  __shared__ __bf16 As[2][BM * BK];   // 2 x 4 KB: [row 0..63][k 0..31]
  __shared__ __bf16 Bs[2][BN * BK];   // 2 x 8 KB: [h 0..127][k 0..31]

  const int tid  = threadIdx.x;
  // XCD-bijective swizzle (1176 = 8*147): each XCD owns a contiguous logical range.
  const int bx   = blockIdx.x;
  const int wgid = (bx & 7) * WG_PER_XCD + (bx >> 3);
  // nblk-inner: 6 consecutive wgid (same XCD) share one A-tile; W (2.36 MB) L2-resident.
  const int mblk = wgid / NBLK_N;
  const int nblk = wgid - mblk * NBLK_N;
  const int m0 = mblk * BM;
  const int n0 = nblk * BN;
  const int wave = tid >> 6, lane = tid & 63;
  const int wm = (wave & 1) * 32;   // wave sub-tile 32(M) x 64(N)
  const int wn = (wave >> 1) * 64;
  const int lrow = lane & 15, lq = lane >> 4;

  f32x4 acc[2][4] = {};

  // A staging: 256 16B chunks/tile, 1 instr/wave. chunk c = tid: row=c>>2, jc=c&3.
  //   tile t covers k in [32t,32t+32): ch=t/8, ph=(t%8)*2+(jc>>1), pw=(jc&1)*8.
  const __bf16* pA;
  {
    const int row = tid >> 2, jc = tid & 3;
    const int m = m0 + row;
    const int bb = m / 196, p = m - bb * 196;
    const int pi = p / 14, pj = p - pi * 14;
    pA = imgb + ((size_t)(bb * 3 * 224 + pi * 16 + (jc >> 1))) * 224 + pj * 16 + (jc & 1) * 8;
  }
  // B staging: 512 chunks/tile, 2 instr/wave. c = wave*128 + s*64 + lane: h=c>>2, jc=c&3.
  const __bf16* pB[2];
  int cB[2];
#pragma unroll
  for (int s = 0; s < 2; ++s) {
    const int c = wave * 128 + s * 64 + lane;
    cB[s] = c;
    const int h = c >> 2, jc = c & 3;
    pB[s] = Wb + (size_t)(n0 + h) * 768 + jc * 8;
  }

  auto stage = [&](int b) {   // b is a literal at every call site -> compile-time
    gload_lds16(pA, (void*)(As[b] + tid * 8));
    gload_lds16(pB[0], (void*)(Bs[b] + cB[0] * 8));
    gload_lds16(pB[1], (void*)(Bs[b] + cB[1] * 8));
  };
  auto advance = [&](int t) {  // t = tile just staged; prepare pointers for t+1
    const int dA = ((t & 7) == 7) ? 47040 : 448;  // +2 image rows, or channel-cross
    pA += dA; pB[0] += BK; pB[1] += BK;
  };
  auto compute = [&](int b) {
    bf16x8 af[2], bf[4];
#pragma unroll
    for (int i = 0; i < 2; ++i)
      af[i] = *(const bf16x8*)&As[b][(wm + i * 16 + lrow) * 32 + lq * 8];
#pragma unroll
    for (int j = 0; j < 4; ++j)
      bf[j] = *(const bf16x8*)&Bs[b][(wn + j * 16 + lrow) * 32 + lq * 8];
#pragma unroll
    for (int i = 0; i < 2; ++i)
#pragma unroll
      for (int j = 0; j < 4; ++j)
        acc[i][j] = __builtin_amdgcn_mfma_f32_16x16x32_bf16(af[i], bf[j], acc[i][j], 0, 0, 0);
  };

  // ---- prologue: stage tile 0 -> buf 0
  stage(0); advance(0);
  __syncthreads();                 // tile 0 resident

  // ---- main: 11 x unroll-by-2 (tiles 0..21 computed, 1..22 staged ahead)
  for (int i = 0; i < 11; ++i) {
    const int t = 2 * i + 1;
    stage(1); advance(t);          // tile t -> buf1, issued BEFORE compute
    compute(0);                    // tile t-1
    __syncthreads();               // buf0 free; tile t loads drained (had full compute)
    stage(0); advance(t + 1);      // tile t+1 -> buf0
    compute(1);                    // tile t
    __syncthreads();
  }
  // ---- epilogue: tiles 22 (buf0) and 23
  stage(1);                        // tile 23 -> buf1
  compute(0);                      // tile 22
  __syncthreads();
  compute(1);                      // tile 23

  // Epilogue: C/D layout col=lane&15, row=(lane>>4)*4+r (round-0-verified convention)
#pragma unroll
  for (int j = 0; j < 4; ++j) {
    const int h  = n0 + wn + j * 16 + lrow;
    const float bv = bias[h];
#pragma unroll
    for (int i = 0; i < 2; ++i) {
      const int mb = m0 + wm + i * 16 + lq * 4;
#pragma unroll
      for (int r = 0; r < 4; ++r) {
        const int m  = mb + r;
        const int bb = m / 196, p = m - bb * 196;
        out[(size_t)(bb * 197 + 1 + p) * 768 + h] = acc[i][j][r] + bv;
      }
    }
  }
}

extern "C" void kernel_launch(void* const* d_in, const int* in_sizes, int n_in,
                              void* d_out, int out_size, void* d_ws, size_t ws_size,
                              hipStream_t stream) {
  const float* images = (const float*)d_in[0];  // [64,3,224,224]
  const float* Wm     = (const float*)d_in[1];  // [768,768]
  const float* b      = (const float*)d_in[2];  // [768]
  const float* cls    = (const float*)d_in[3];  // [1,768]
  float* out = (float*)d_out;                   // [64,197,768]

  __bf16* imgb = (__bf16*)d_ws;                   // 19.27 MB
  __bf16* Wb   = imgb + (size_t)IMG_ELEMS;        // 1.18 MB
  (void)in_sizes; (void)n_in; (void)out_size; (void)ws_size;

  prep_kernel<<<A_BLOCKS + W_BLOCKS + CLS_BLOCKS, 256, 0, stream>>>(
      images, Wm, cls, out, imgb, Wb);
  gemm_kernel<<<NWG, 256, 0, stream>>>(imgb, Wb, b, out);
}